// Round 15
// baseline (235.572 us; speedup 1.0000x reference)
//
#include <hip/hip_runtime.h>

typedef unsigned short ushort;
typedef __bf16 bf16x8 __attribute__((ext_vector_type(8)));
typedef float f32x4 __attribute__((ext_vector_type(4)));
typedef unsigned short us8v __attribute__((ext_vector_type(8)));

__device__ __forceinline__ ushort f2bf(float f) {
  unsigned u = __builtin_bit_cast(unsigned, f);
  u += 0x7FFFu + ((u >> 16) & 1u);
  return (ushort)(u >> 16);
}

__device__ __forceinline__ bf16x8 ld_bf16x8(const ushort* p) {
  uint4 v = *(const uint4*)p;
  return __builtin_bit_cast(bf16x8, v);
}

// async global->LDS, 16B per lane (dest must be linear: base + lane*16)
__device__ __forceinline__ void gl16(const ushort* g, ushort* l) {
  __builtin_amdgcn_global_load_lds(
      (const __attribute__((address_space(1))) void*)g,
      (__attribute__((address_space(3))) void*)l, 16, 0, 0);
}

// ---------------- pack X fp32 -> bf16 ----------------
__global__ __launch_bounds__(256) void pack_x(const float* __restrict__ in,
                                              ushort* __restrict__ out) {
  long i = (long)blockIdx.x * 256 + threadIdx.x;
  const float4* s = (const float4*)in;
  float4 a = s[i * 2], b = s[i * 2 + 1];
  us8v o;
  o[0] = f2bf(a.x); o[1] = f2bf(a.y); o[2] = f2bf(a.z); o[3] = f2bf(a.w);
  o[4] = f2bf(b.x); o[5] = f2bf(b.y); o[6] = f2bf(b.z); o[7] = f2bf(b.w);
  *(us8v*)&out[i * 8] = o;
}

// ---------------- transpose+pack weights: dst[c][r] = src[r][c]*scale (bf16) ----
__global__ __launch_bounds__(256) void transpose_pack(
    const float* __restrict__ src, ushort* __restrict__ dst,
    int sC, int dLd, long sBatch, long dBatch, float scale) {
  src += (long)blockIdx.z * sBatch;
  dst += (long)blockIdx.z * dBatch;
  const int r0 = blockIdx.y * 64, c0 = blockIdx.x * 64;
  __shared__ ushort T[64 * 68];
  const int t = threadIdx.x;
#pragma unroll
  for (int i = 0; i < 4; ++i) {
    int ch = t + 256 * i;
    int r = ch >> 4, c4 = ch & 15;
    float4 v = *(const float4*)&src[(long)(r0 + r) * sC + c0 + c4 * 4];
    T[(c4 * 4 + 0) * 68 + r] = f2bf(v.x * scale);
    T[(c4 * 4 + 1) * 68 + r] = f2bf(v.y * scale);
    T[(c4 * 4 + 2) * 68 + r] = f2bf(v.z * scale);
    T[(c4 * 4 + 3) * 68 + r] = f2bf(v.w * scale);
  }
  __syncthreads();
#pragma unroll
  for (int i = 0; i < 4; ++i) {
    int ch = t + 256 * i;
    int c = ch >> 4, r4 = ch & 15;
    ushort4 o;
    o.x = T[c * 68 + r4 * 4 + 0];
    o.y = T[c * 68 + r4 * 4 + 1];
    o.z = T[c * 68 + r4 * 4 + 2];
    o.w = T[c * 68 + r4 * 4 + 3];
    *(ushort4*)&dst[(long)(c0 + c) * dLd + r0 + r4 * 4] = o;
  }
}

// ------ 256x128 bf16 MFMA GEMM, depth-2 counted-vmcnt pipeline (T4) ----------
// 8 waves (4M x 2N), 3 LDS buffers (144 KB). Per K-step: stage(kt+2) async into
// buf (kt+2)%3, compute(kt%3), then s_waitcnt vmcnt(6) + s_barrier: only
// stage(kt+1) is guaranteed landed; stage(kt+2)'s 6 loads stay IN FLIGHT across
// the barrier (never drain to 0 in the main loop) -> every tile's loads get two
// full compute phases of latency cover. Tail uses vmcnt(0).
// XOR bank swizzle both sides. SWZ=0: batch z pinned to XCD. SWZ=1: band
// supertile per XCD (A-slab + B col-slice L2-resident).
// EPI 0: scatter Q/K ([B,H,S,64]) + Vt ([B,D,S]); EPI 1: bf16 C; EPI 2: fp32 C
template <int EPI, bool CAUSAL, int SWZ>
__global__ __launch_bounds__(512, 1) void gemm3b(
    const ushort* __restrict__ A, const ushort* __restrict__ Bt,
    int N, int K, long aB, long bB,
    ushort* __restrict__ O_q, ushort* __restrict__ O_k, ushort* __restrict__ O_v,
    ushort* __restrict__ O_b, long oB,
    float* __restrict__ O_f) {
  __shared__ __align__(16) ushort As[3][256 * 64];  // 3 x 32 KB
  __shared__ __align__(16) ushort Bs[3][128 * 64];  // 3 x 16 KB
  const int tid = threadIdx.x;
  const int lane = tid & 63, w = tid >> 6;
  const int lr = lane & 15, lg = lane >> 4;

  // XCD assignment: hw-linear id %8 = XCD
  const int nx = gridDim.x, ny = gridDim.y;
  long hw = blockIdx.x + (long)nx * (blockIdx.y + (long)ny * blockIdx.z);
  int k8 = (int)(hw & 7);
  long l = hw >> 3;
  int bx, by, z;
  if (SWZ == 1) {              // band supertile: XCD owns ny/8 consecutive rows
    const int BH = ny >> 3;
    by = k8 * BH + (int)(l % BH);
    bx = (int)(l / BH);
    z = 0;
  } else {                     // XCD owns batch z (requires gridDim.z == 8)
    z = k8;
    by = (int)(l % ny);
    bx = (int)(l / ny);
  }

  const int row0 = by * 256, col0 = bx * 128;
  A += (long)z * aB;
  Bt += (long)z * bB;
  const int wr = (w >> 1) * 64, wc = (w & 1) * 64;

  f32x4 acc[4][4] = {};
  const int kmax = CAUSAL ? (K < row0 + 256 ? K : row0 + 256) : K;
  const int nk = kmax >> 6;

  auto stage = [&](int buf, int kt) {      // 6 loads per thread (A:4, B:2)
    const int k0 = kt << 6;
#pragma unroll
    for (int j = 0; j < 4; ++j) {
      int c = tid + 512 * j;
      int r = c >> 3, c8 = (c & 7) ^ (r & 7);
      gl16(&A[(long)(row0 + r) * K + k0 + c8 * 8], &As[buf][c * 8]);
    }
#pragma unroll
    for (int j = 0; j < 2; ++j) {
      int c = tid + 512 * j;
      int r = c >> 3, c8 = (c & 7) ^ (r & 7);
      gl16(&Bt[(long)(col0 + r) * K + k0 + c8 * 8], &Bs[buf][c * 8]);
    }
  };
  auto compute = [&](int buf) {
#pragma unroll
    for (int kk = 0; kk < 2; ++kk) {
      bf16x8 af[4], bfr[4];
#pragma unroll
      for (int m = 0; m < 4; ++m) {
        int row = wr + m * 16 + lr;
        int c8 = (kk * 4 + lg) ^ (row & 7);
        af[m] = ld_bf16x8(&As[buf][row * 64 + c8 * 8]);
      }
#pragma unroll
      for (int n = 0; n < 4; ++n) {
        int row = wc + n * 16 + lr;
        int c8 = (kk * 4 + lg) ^ (row & 7);
        bfr[n] = ld_bf16x8(&Bs[buf][row * 64 + c8 * 8]);
      }
      __builtin_amdgcn_s_setprio(1);
#pragma unroll
      for (int m = 0; m < 4; ++m)
#pragma unroll
        for (int n = 0; n < 4; ++n)
          acc[m][n] = __builtin_amdgcn_mfma_f32_16x16x32_bf16(af[m], bfr[n], acc[m][n], 0, 0, 0);
      __builtin_amdgcn_s_setprio(0);
    }
  };

  // prologue: two stages in flight; wait only for the first (vmcnt(6))
  stage(0, 0);
  stage(1, 1);
  asm volatile("s_waitcnt vmcnt(6)" ::: "memory");
  __builtin_amdgcn_s_barrier();
  __builtin_amdgcn_sched_barrier(0);
  for (int kt = 0; kt < nk; ++kt) {
    if (kt + 2 < nk) stage((kt + 2) % 3, kt + 2);  // keep 6 loads in flight
    compute(kt % 3);
    if (kt < nk - 1) {
      if (kt + 2 < nk) {
        asm volatile("s_waitcnt vmcnt(6)" ::: "memory");  // (kt+1) landed; (kt+2) flying
      } else {
        asm volatile("s_waitcnt vmcnt(0)" ::: "memory");  // tail: drain
      }
      __builtin_amdgcn_s_barrier();
      __builtin_amdgcn_sched_barrier(0);
    }
  }

#pragma unroll
  for (int m = 0; m < 4; ++m)
#pragma unroll
    for (int n = 0; n < 4; ++n)
#pragma unroll
      for (int r = 0; r < 4; ++r) {
        int gr = row0 + wr + m * 16 + lg * 4 + r;
        int gc = col0 + wc + n * 16 + lr;
        float v = acc[m][n][r];
        if (EPI == 0) {
          int b = gr >> 10, s = gr & 1023;
          if (gc < 1024) {
            int h = gc >> 6, kq = gc & 63;
            O_q[(((long)(b * 16 + h) << 10) + s) * 64 + kq] = f2bf(v);
          } else if (gc < 2048) {
            int n2 = gc - 1024;
            int h = n2 >> 6, kq = n2 & 63;
            O_k[(((long)(b * 16 + h) << 10) + s) * 64 + kq] = f2bf(v);
          } else {
            int e = gc - 2048;
            O_v[((long)(b << 10) + e) * 1024 + s] = f2bf(v);
          }
        } else if (EPI == 1) {
          (O_b + (long)z * oB)[(long)gr * N + gc] = f2bf(v);
        } else {
          O_f[(long)gr * N + gc] = v;
        }
      }
}

// ---------------- fused masked softmax, head-averaged attention (v6) ----------
// grid (32, 8) = 256 blocks (1/CU, 1 round), 512 threads = 8 waves. Block owns
// the PAIR (qt = x2, qt = 63-x2): uniform work, shared K staging. K staged per
// head into double-buffered LDS halves; stage drains covered by QK phases.
__global__ __launch_bounds__(512, 2) void attn16(
    const ushort* __restrict__ Qb, const ushort* __restrict__ Kb,
    const float* __restrict__ mask, float* __restrict__ attn_out,
    ushort* __restrict__ attnb) {
  __shared__ __align__(16) ushort Ks[2][4 * 128 * 64];  // 2 x 64 KB
  __shared__ float redS[2][8][16];
  const int tid = threadIdx.x;
  const int lane = tid & 63, w = tid >> 6;   // wave owns s-cols w*16+lr per 128-strip
  const int lr = lane & 15, lg = lane >> 4;
  const int hw = blockIdx.x + 32 * blockIdx.y;
  const int b = hw & 7;                      // linear id %8 = XCD: pin batch
  const int x2 = hw >> 3;                    // 0..31
  const int q0a = x2 * 16;                   // light tile (strips 0..3 only)
  const int q0b = (63 - x2) * 16;            // heavy tile (512..1008)
  const int NTb = ((63 - x2) >> 3) + 1;      // heavy strips needed: 5..8
  const int n1 = (NTb - 4) << 10;            // g1 chunk count (1024..4096)
  const int NTWa = (x2 >> 4) * 2 + 2;        // strips AV's 256-row tile reads
  const int NTWb = ((63 - x2) >> 4) * 2 + 2;

  float mqa[4], mqb[4], ms[8];
#pragma unroll
  for (int r = 0; r < 4; ++r) {
    mqa[r] = mask[b * 1024 + q0a + lg * 4 + r];
    mqb[r] = mask[b * 1024 + q0b + lg * 4 + r];
  }
#pragma unroll
  for (int t = 0; t < 8; ++t) ms[t] = mask[b * 1024 + t * 128 + w * 16 + lr];

  auto stageG = [&](int buf, int t0, int nch, int h) {
    const long hb = ((long)(b * 16 + h)) << 10;
#pragma unroll 2
    for (int i = tid; i < nch; i += 512) {
      int j = i >> 10, r = (i >> 3) & 127, c8 = i & 7;
      gl16(&Kb[(hb + (t0 + j) * 128 + r) * 64 + ((c8 ^ (r & 7)) << 3)],
           &Ks[buf][i * 8]);
    }
  };

  const int row = w * 16 + lr;
  const int cs0 = ((0 + lg) ^ (row & 7)) * 8;   // swizzled byte cols kk=0/1
  const int cs1 = ((4 + lg) ^ (row & 7)) * 8;

  stageG(0, 0, 4096, 0);
  __syncthreads();   // prologue drain

  f32x4 acca[4] = {};
  f32x4 accb[8] = {};
#pragma unroll 1
  for (int h = 0; h < 16; ++h) {
    const long hb = ((long)(b * 16 + h)) << 10;
    const bf16x8 qa0 = ld_bf16x8(&Qb[(hb + q0a + lr) * 64 + lg * 8]);
    const bf16x8 qa1 = ld_bf16x8(&Qb[(hb + q0a + lr) * 64 + 32 + lg * 8]);
    const bf16x8 qb0 = ld_bf16x8(&Qb[(hb + q0b + lr) * 64 + lg * 8]);
    const bf16x8 qb1 = ld_bf16x8(&Qb[(hb + q0b + lr) * 64 + 32 + lg * 8]);

    stageG(1, 4, n1, h);   // issue g1 strips; covered by QK(g0) below

    f32x4 sca[4], scb[8];
    float psa[4] = {0.f, 0.f, 0.f, 0.f}, psb[4] = {0.f, 0.f, 0.f, 0.f};
    // ---- QK group 0: strips 0..3 from Ks[0] ----
#pragma unroll
    for (int t = 0; t < 4; ++t) {
      const int sb = t * 128 + w * 16;
      const ushort* kr = &Ks[0][(t * 128 + row) * 64];
      bf16x8 k0 = ld_bf16x8(kr + cs0);
      bf16x8 k1 = ld_bf16x8(kr + cs1);
      {  // heavy tile: sb <= 496 < 512 <= q0b always
        f32x4 d = {};
        d = __builtin_amdgcn_mfma_f32_16x16x32_bf16(qb0, k0, d, 0, 0, 0);
        d = __builtin_amdgcn_mfma_f32_16x16x32_bf16(qb1, k1, d, 0, 0, 0);
#pragma unroll
        for (int r = 0; r < 4; ++r) {
          float e = __expf(d[r]) * (mqb[r] * ms[t]);
          scb[t][r] = e;
          psb[r] += e;
        }
      }
      if (sb <= q0a) {  // light tile
        f32x4 d = {};
        d = __builtin_amdgcn_mfma_f32_16x16x32_bf16(qa0, k0, d, 0, 0, 0);
        d = __builtin_amdgcn_mfma_f32_16x16x32_bf16(qa1, k1, d, 0, 0, 0);
#pragma unroll
        for (int r = 0; r < 4; ++r) {
          float e = __expf(d[r]) * (mqa[r] * ms[t]);
          if (sb == q0a) e = (lr <= lg * 4 + r) ? e : 0.f;
          sca[t][r] = e;
          psa[r] += e;
        }
      }
    }
    __syncthreads();   // drain g1 stage; Ks[0] reads done

    if (h < 15) stageG(0, 0, 4096, h + 1);  // issue next head g0; covered by QK(g1)

    // ---- QK group 1: strips 4..7 from Ks[1] ----
#pragma unroll
    for (int t = 4; t < 8; ++t) {
      const int sb = t * 128 + w * 16;
      if (sb <= q0b) {
        const ushort* kr = &Ks[1][((t - 4) * 128 + row) * 64];
        bf16x8 k0 = ld_bf16x8(kr + cs0);
        bf16x8 k1 = ld_bf16x8(kr + cs1);
        f32x4 d = {};
        d = __builtin_amdgcn_mfma_f32_16x16x32_bf16(qb0, k0, d, 0, 0, 0);
        d = __builtin_amdgcn_mfma_f32_16x16x32_bf16(qb1, k1, d, 0, 0, 0);
#pragma unroll
        for (int r = 0; r < 4; ++r) {
          float e = __expf(d[r]) * (mqb[r] * ms[t]);
          if (sb == q0b) e = (lr <= lg * 4 + r) ? e : 0.f;
          scb[t][r] = e;
          psb[r] += e;
        }
      }
    }
    // row-sums: 16-lane shfl reduce, then cross-wave via LDS
#pragma unroll
    for (int r = 0; r < 4; ++r) {
      psa[r] += __shfl_xor(psa[r], 1);
      psa[r] += __shfl_xor(psa[r], 2);
      psa[r] += __shfl_xor(psa[r], 4);
      psa[r] += __shfl_xor(psa[r], 8);
      psb[r] += __shfl_xor(psb[r], 1);
      psb[r] += __shfl_xor(psb[r], 2);
      psb[r] += __shfl_xor(psb[r], 4);
      psb[r] += __shfl_xor(psb[r], 8);
    }
    if (lr == 0) {
#pragma unroll
      for (int r = 0; r < 4; ++r) {
        redS[0][w][lg * 4 + r] = psa[r];
        redS[1][w][lg * 4 + r] = psb[r];
      }
    }
    __syncthreads();  // drain next-g0 stage; Ks[1] reads done; redS visible

#pragma unroll
    for (int r = 0; r < 4; ++r) {
      float ta = 0.f, tb = 0.f;
#pragma unroll
      for (int ww = 0; ww < 8; ++ww) {
        ta += redS[0][ww][lg * 4 + r];
        tb += redS[1][ww][lg * 4 + r];
      }
      float ra = __builtin_amdgcn_rcpf(ta);
      float rb = __builtin_amdgcn_rcpf(tb);
#pragma unroll
      for (int t = 0; t < 4; ++t) {
        const int sb = t * 128 + w * 16;
        if (sb <= q0a) acca[t][r] += sca[t][r] * ra;
      }
#pragma unroll
      for (int t = 0; t < 8; ++t) {
        const int sb = t * 128 + w * 16;
        if (sb <= q0b) accb[t][r] += scb[t][r] * rb;
      }
    }
  }  // heads

  // write fp32 attn_avg (d_out) + bf16 copy for strips the AV GEMM reads
#pragma unroll
  for (int t = 0; t < 8; ++t) {
    int s = t * 128 + w * 16 + lr;
#pragma unroll
    for (int r = 0; r < 4; ++r) {
      {
        int q = q0a + lg * 4 + r;
        float v = (t < 4 ? acca[t][r] : 0.f) * 0.0625f;
        long o = ((long)(b * 1024 + q) << 10) + s;
        attn_out[o] = v;
        if (t < NTWa) attnb[o] = f2bf(v);
      }
      {
        int q = q0b + lg * 4 + r;
        float v = accb[t][r] * 0.0625f;
        long o = ((long)(b * 1024 + q) << 10) + s;
        attn_out[o] = v;
        if (t < NTWb) attnb[o] = f2bf(v);
      }
    }
  }
}

// ---------------- launch ----------------
extern "C" void kernel_launch(void* const* d_in, const int* in_sizes, int n_in,
                              void* d_out, int out_size, void* d_ws, size_t ws_size,
                              hipStream_t stream) {
  const float* inputs = (const float*)d_in[0];
  const float* mask   = (const float*)d_in[1];
  const float* W_q    = (const float*)d_in[2];
  const float* W_k    = (const float*)d_in[3];
  const float* W_v    = (const float*)d_in[4];
  const float* W_o    = (const float*)d_in[5];
  float* out = (float*)d_out;

  ushort* Xb    = (ushort*)d_ws;            // [8192][1024]
  ushort* WqkvT = Xb + 8192L * 1024;        // [3072][1024]  (B^T layout)
  ushort* WoT   = WqkvT + 3072L * 1024;     // [1024][1024]
  ushort* Qb    = WoT + 1024L * 1024;       // [B,H,S,64]
  ushort* Kb    = Qb + 8L * 16 * 1024 * 64; // [B,H,S,64]
  ushort* Vt    = Kb + 8L * 16 * 1024 * 64; // [B,D,S]
  ushort* attnb = Vt + 8L * 1024 * 1024;    // [B,S,S]
  ushort* Houtb = attnb + 8L * 1024 * 1024; // [B,S,D]

  pack_x<<<4096, 256, 0, stream>>>(inputs, Xb);
  transpose_pack<<<dim3(1, 16, 16), 256, 0, stream>>>(W_q, WqkvT, 64, 1024,
                                                      65536L, 64L * 1024, 0.125f);
  transpose_pack<<<dim3(1, 16, 16), 256, 0, stream>>>(W_k, WqkvT + 1024L * 1024, 64, 1024,
                                                      65536L, 64L * 1024, 1.0f);
  transpose_pack<<<dim3(16, 16, 1), 256, 0, stream>>>(W_v, WqkvT + 2048L * 1024, 1024, 1024,
                                                      0L, 0L, 1.0f);
  transpose_pack<<<dim3(16, 16, 1), 256, 0, stream>>>(W_o, WoT, 1024, 1024,
                                                      0L, 0L, 1.0f);
  // QKV projection: [8192,1024] x [1024,3072], 256x128 tiles, depth-2 counted
  // pipeline, band-supertile XCD mapping (SWZ=1). 768 blocks.
  gemm3b<0, false, 1><<<dim3(24, 32, 1), 512, 0, stream>>>(
      Xb, WqkvT, 3072, 1024, 0L, 0L, Qb, Kb, Vt, nullptr, 0L, nullptr);
  // masked softmax, head-avg: 256 blocks, paired q-tiles
  attn16<<<dim3(32, 8), 512, 0, stream>>>(Qb, Kb, mask, out + 8388608L, attnb);
  // Hout = attn_avg @ V (causal K-limit), per batch (SWZ=0: z pinned to XCD)
  gemm3b<1, true, 0><<<dim3(8, 4, 8), 512, 0, stream>>>(
      attnb, Vt, 1024, 1024, 1048576L, 1048576L,
      nullptr, nullptr, nullptr, Houtb, 1048576L, nullptr);
  // output = Hout @ W_o, band-supertile mapping
  gemm3b<2, false, 1><<<dim3(8, 32, 1), 512, 0, stream>>>(
      Houtb, WoT, 1024, 1024, 0L, 0L,
      nullptr, nullptr, nullptr, nullptr, 0L, out);
}

// Round 16
// 225.244 us; speedup vs baseline: 1.0459x; 1.0459x over previous
//
#include <hip/hip_runtime.h>

typedef unsigned short ushort;
typedef __bf16 bf16x8 __attribute__((ext_vector_type(8)));
typedef float f32x4 __attribute__((ext_vector_type(4)));
typedef unsigned short us8v __attribute__((ext_vector_type(8)));

__device__ __forceinline__ ushort f2bf(float f) {
  unsigned u = __builtin_bit_cast(unsigned, f);
  u += 0x7FFFu + ((u >> 16) & 1u);
  return (ushort)(u >> 16);
}

__device__ __forceinline__ bf16x8 ld_bf16x8(const ushort* p) {
  uint4 v = *(const uint4*)p;
  return __builtin_bit_cast(bf16x8, v);
}

// async global->LDS, 16B per lane (dest must be linear: base + lane*16)
__device__ __forceinline__ void gl16(const ushort* g, ushort* l) {
  __builtin_amdgcn_global_load_lds(
      (const __attribute__((address_space(1))) void*)g,
      (__attribute__((address_space(3))) void*)l, 16, 0, 0);
}

// ---------------- pack fp32 -> bf16 (any 8-multiple array) ----------------
__global__ __launch_bounds__(256) void pack_x(const float* __restrict__ in,
                                              ushort* __restrict__ out) {
  long i = (long)blockIdx.x * 256 + threadIdx.x;
  const float4* s = (const float4*)in;
  float4 a = s[i * 2], b = s[i * 2 + 1];
  us8v o;
  o[0] = f2bf(a.x); o[1] = f2bf(a.y); o[2] = f2bf(a.z); o[3] = f2bf(a.w);
  o[4] = f2bf(b.x); o[5] = f2bf(b.y); o[6] = f2bf(b.z); o[7] = f2bf(b.w);
  *(us8v*)&out[i * 8] = o;
}

// ---------------- sum 8 fp32 planes -> bf16 (Wvo split-K reduction) ---------
__global__ __launch_bounds__(256) void sum8_pack(const float* __restrict__ p,
                                                 ushort* __restrict__ out) {
  int i = (blockIdx.x * 256 + threadIdx.x) * 4;
  float4 s = *(const float4*)&p[i];
#pragma unroll
  for (int z = 1; z < 8; ++z) {
    float4 v = *(const float4*)&p[(long)z * 1048576 + i];
    s.x += v.x; s.y += v.y; s.z += v.z; s.w += v.w;
  }
  ushort4 o;
  o.x = f2bf(s.x); o.y = f2bf(s.y); o.z = f2bf(s.z); o.w = f2bf(s.w);
  *(ushort4*)&out[i] = o;
}

// ---------------- transpose+pack: dst[c][r] = src[r][c]*scale (bf16) --------
__global__ __launch_bounds__(256) void transpose_pack(
    const float* __restrict__ src, ushort* __restrict__ dst,
    int sC, int dLd, long sBatch, long dBatch, float scale) {
  src += (long)blockIdx.z * sBatch;
  dst += (long)blockIdx.z * dBatch;
  const int r0 = blockIdx.y * 64, c0 = blockIdx.x * 64;
  __shared__ ushort T[64 * 68];
  const int t = threadIdx.x;
#pragma unroll
  for (int i = 0; i < 4; ++i) {
    int ch = t + 256 * i;
    int r = ch >> 4, c4 = ch & 15;
    float4 v = *(const float4*)&src[(long)(r0 + r) * sC + c0 + c4 * 4];
    T[(c4 * 4 + 0) * 68 + r] = f2bf(v.x * scale);
    T[(c4 * 4 + 1) * 68 + r] = f2bf(v.y * scale);
    T[(c4 * 4 + 2) * 68 + r] = f2bf(v.z * scale);
    T[(c4 * 4 + 3) * 68 + r] = f2bf(v.w * scale);
  }
  __syncthreads();
#pragma unroll
  for (int i = 0; i < 4; ++i) {
    int ch = t + 256 * i;
    int c = ch >> 4, r4 = ch & 15;
    ushort4 o;
    o.x = T[c * 68 + r4 * 4 + 0];
    o.y = T[c * 68 + r4 * 4 + 1];
    o.z = T[c * 68 + r4 * 4 + 2];
    o.w = T[c * 68 + r4 * 4 + 3];
    *(ushort4*)&dst[(long)(c0 + c) * dLd + r0 + r4 * 4] = o;
  }
}

// ------ 256x128 bf16 MFMA GEMM, depth-2 counted-vmcnt pipeline --------------
// 8 waves (4M x 2N), 3 LDS buffers. XOR bank swizzle both sides.
// SWZ=0: z = hw&7 (XCD owns z); SWZ=1: band supertile per XCD, z=0.
// KSPLIT>1: z = k-chunk index, A/Bt shifted by z*aB elements (k-offset).
// EPI 0: scatter Q/K ([B,H,S,64]); EPI 1: bf16 C (+z*oB); EPI 2: fp32 C (+z*oB)
template <int EPI, bool CAUSAL, int SWZ, int KSPLIT>
__global__ __launch_bounds__(512, 1) void gemm3b(
    const ushort* __restrict__ A, const ushort* __restrict__ Bt,
    int N, int K, long aB, long bB,
    ushort* __restrict__ O_q, ushort* __restrict__ O_k,
    ushort* __restrict__ O_b, long oB,
    float* __restrict__ O_f) {
  __shared__ __align__(16) ushort As[3][256 * 64];  // 3 x 32 KB
  __shared__ __align__(16) ushort Bs[3][128 * 64];  // 3 x 16 KB
  const int tid = threadIdx.x;
  const int lane = tid & 63, w = tid >> 6;
  const int lr = lane & 15, lg = lane >> 4;

  // XCD assignment: hw-linear id %8 = XCD
  const int nx = gridDim.x, ny = gridDim.y;
  long hw = blockIdx.x + (long)nx * (blockIdx.y + (long)ny * blockIdx.z);
  int k8 = (int)(hw & 7);
  long l = hw >> 3;
  int bx, by, z;
  if (SWZ == 1) {              // band supertile: XCD owns ny/8 consecutive rows
    const int BH = ny >> 3;
    by = k8 * BH + (int)(l % BH);
    bx = (int)(l / BH);
    z = 0;
  } else {                     // XCD owns z (batch or k-chunk); gridDim.z == 8
    z = k8;
    by = (int)(l % ny);
    bx = (int)(l / ny);
  }

  const int row0 = by * 256, col0 = bx * 128;
  A += (long)z * aB;
  Bt += (long)z * bB;
  const int wr = (w >> 1) * 64, wc = (w & 1) * 64;

  f32x4 acc[4][4] = {};
  const int kmax = CAUSAL ? (K < row0 + 256 ? K : row0 + 256) : K;
  const int nk = (kmax >> 6) / KSPLIT;

  auto stage = [&](int buf, int kt) {      // 6 loads per thread (A:4, B:2)
    const int k0 = kt << 6;
#pragma unroll
    for (int j = 0; j < 4; ++j) {
      int c = tid + 512 * j;
      int r = c >> 3, c8 = (c & 7) ^ (r & 7);
      gl16(&A[(long)(row0 + r) * K + k0 + c8 * 8], &As[buf][c * 8]);
    }
#pragma unroll
    for (int j = 0; j < 2; ++j) {
      int c = tid + 512 * j;
      int r = c >> 3, c8 = (c & 7) ^ (r & 7);
      gl16(&Bt[(long)(col0 + r) * K + k0 + c8 * 8], &Bs[buf][c * 8]);
    }
  };
  auto compute = [&](int buf) {
#pragma unroll
    for (int kk = 0; kk < 2; ++kk) {
      bf16x8 af[4], bfr[4];
#pragma unroll
      for (int m = 0; m < 4; ++m) {
        int row = wr + m * 16 + lr;
        int c8 = (kk * 4 + lg) ^ (row & 7);
        af[m] = ld_bf16x8(&As[buf][row * 64 + c8 * 8]);
      }
#pragma unroll
      for (int n = 0; n < 4; ++n) {
        int row = wc + n * 16 + lr;
        int c8 = (kk * 4 + lg) ^ (row & 7);
        bfr[n] = ld_bf16x8(&Bs[buf][row * 64 + c8 * 8]);
      }
      __builtin_amdgcn_s_setprio(1);
#pragma unroll
      for (int m = 0; m < 4; ++m)
#pragma unroll
        for (int n = 0; n < 4; ++n)
          acc[m][n] = __builtin_amdgcn_mfma_f32_16x16x32_bf16(af[m], bfr[n], acc[m][n], 0, 0, 0);
      __builtin_amdgcn_s_setprio(0);
    }
  };

  stage(0, 0);
  stage(1, 1);
  asm volatile("s_waitcnt vmcnt(6)" ::: "memory");
  __builtin_amdgcn_s_barrier();
  __builtin_amdgcn_sched_barrier(0);
  for (int kt = 0; kt < nk; ++kt) {
    if (kt + 2 < nk) stage((kt + 2) % 3, kt + 2);
    compute(kt % 3);
    if (kt < nk - 1) {
      if (kt + 2 < nk) {
        asm volatile("s_waitcnt vmcnt(6)" ::: "memory");
      } else {
        asm volatile("s_waitcnt vmcnt(0)" ::: "memory");
      }
      __builtin_amdgcn_s_barrier();
      __builtin_amdgcn_sched_barrier(0);
    }
  }

#pragma unroll
  for (int m = 0; m < 4; ++m)
#pragma unroll
    for (int n = 0; n < 4; ++n)
#pragma unroll
      for (int r = 0; r < 4; ++r) {
        int gr = row0 + wr + m * 16 + lg * 4 + r;
        int gc = col0 + wc + n * 16 + lr;
        float v = acc[m][n][r];
        if (EPI == 0) {
          int b = gr >> 10, s = gr & 1023;
          if (gc < 1024) {
            int h = gc >> 6, kq = gc & 63;
            O_q[(((long)(b * 16 + h) << 10) + s) * 64 + kq] = f2bf(v);
          } else {
            int n2 = gc - 1024;
            int h = n2 >> 6, kq = n2 & 63;
            O_k[(((long)(b * 16 + h) << 10) + s) * 64 + kq] = f2bf(v);
          }
        } else if (EPI == 1) {
          (O_b + (long)z * oB)[(long)gr * N + gc] = f2bf(v);
        } else {
          (O_f + (long)z * oB)[(long)gr * N + gc] = v;
        }
      }
}

// ---------------- fused masked softmax, head-averaged attention (v6) ----------
// grid (32, 8) = 256 blocks (1/CU, 1 round), 512 threads = 8 waves. Block owns
// the PAIR (qt = x2, qt = 63-x2): uniform work, shared K staging. K staged per
// head into double-buffered LDS halves; stage drains covered by QK phases.
__global__ __launch_bounds__(512, 2) void attn16(
    const ushort* __restrict__ Qb, const ushort* __restrict__ Kb,
    const float* __restrict__ mask, float* __restrict__ attn_out,
    ushort* __restrict__ attnb) {
  __shared__ __align__(16) ushort Ks[2][4 * 128 * 64];  // 2 x 64 KB
  __shared__ float redS[2][8][16];
  const int tid = threadIdx.x;
  const int lane = tid & 63, w = tid >> 6;   // wave owns s-cols w*16+lr per 128-strip
  const int lr = lane & 15, lg = lane >> 4;
  const int hw = blockIdx.x + 32 * blockIdx.y;
  const int b = hw & 7;                      // linear id %8 = XCD: pin batch
  const int x2 = hw >> 3;                    // 0..31
  const int q0a = x2 * 16;                   // light tile (strips 0..3 only)
  const int q0b = (63 - x2) * 16;            // heavy tile (512..1008)
  const int NTb = ((63 - x2) >> 3) + 1;      // heavy strips needed: 5..8
  const int n1 = (NTb - 4) << 10;            // g1 chunk count (1024..4096)
  const int NTWa = (x2 >> 4) * 2 + 2;        // strips AV's 256-row tile reads
  const int NTWb = ((63 - x2) >> 4) * 2 + 2;

  float mqa[4], mqb[4], ms[8];
#pragma unroll
  for (int r = 0; r < 4; ++r) {
    mqa[r] = mask[b * 1024 + q0a + lg * 4 + r];
    mqb[r] = mask[b * 1024 + q0b + lg * 4 + r];
  }
#pragma unroll
  for (int t = 0; t < 8; ++t) ms[t] = mask[b * 1024 + t * 128 + w * 16 + lr];

  auto stageG = [&](int buf, int t0, int nch, int h) {
    const long hb = ((long)(b * 16 + h)) << 10;
#pragma unroll 2
    for (int i = tid; i < nch; i += 512) {
      int j = i >> 10, r = (i >> 3) & 127, c8 = i & 7;
      gl16(&Kb[(hb + (t0 + j) * 128 + r) * 64 + ((c8 ^ (r & 7)) << 3)],
           &Ks[buf][i * 8]);
    }
  };

  const int row = w * 16 + lr;
  const int cs0 = ((0 + lg) ^ (row & 7)) * 8;   // swizzled byte cols kk=0/1
  const int cs1 = ((4 + lg) ^ (row & 7)) * 8;

  stageG(0, 0, 4096, 0);
  __syncthreads();   // prologue drain

  f32x4 acca[4] = {};
  f32x4 accb[8] = {};
#pragma unroll 1
  for (int h = 0; h < 16; ++h) {
    const long hb = ((long)(b * 16 + h)) << 10;
    const bf16x8 qa0 = ld_bf16x8(&Qb[(hb + q0a + lr) * 64 + lg * 8]);
    const bf16x8 qa1 = ld_bf16x8(&Qb[(hb + q0a + lr) * 64 + 32 + lg * 8]);
    const bf16x8 qb0 = ld_bf16x8(&Qb[(hb + q0b + lr) * 64 + lg * 8]);
    const bf16x8 qb1 = ld_bf16x8(&Qb[(hb + q0b + lr) * 64 + 32 + lg * 8]);

    stageG(1, 4, n1, h);   // issue g1 strips; covered by QK(g0) below

    f32x4 sca[4], scb[8];
    float psa[4] = {0.f, 0.f, 0.f, 0.f}, psb[4] = {0.f, 0.f, 0.f, 0.f};
    // ---- QK group 0: strips 0..3 from Ks[0] ----
#pragma unroll
    for (int t = 0; t < 4; ++t) {
      const int sb = t * 128 + w * 16;
      const ushort* kr = &Ks[0][(t * 128 + row) * 64];
      bf16x8 k0 = ld_bf16x8(kr + cs0);
      bf16x8 k1 = ld_bf16x8(kr + cs1);
      {  // heavy tile: sb <= 496 < 512 <= q0b always
        f32x4 d = {};
        d = __builtin_amdgcn_mfma_f32_16x16x32_bf16(qb0, k0, d, 0, 0, 0);
        d = __builtin_amdgcn_mfma_f32_16x16x32_bf16(qb1, k1, d, 0, 0, 0);
#pragma unroll
        for (int r = 0; r < 4; ++r) {
          float e = __expf(d[r]) * (mqb[r] * ms[t]);
          scb[t][r] = e;
          psb[r] += e;
        }
      }
      if (sb <= q0a) {  // light tile
        f32x4 d = {};
        d = __builtin_amdgcn_mfma_f32_16x16x32_bf16(qa0, k0, d, 0, 0, 0);
        d = __builtin_amdgcn_mfma_f32_16x16x32_bf16(qa1, k1, d, 0, 0, 0);
#pragma unroll
        for (int r = 0; r < 4; ++r) {
          float e = __expf(d[r]) * (mqa[r] * ms[t]);
          if (sb == q0a) e = (lr <= lg * 4 + r) ? e : 0.f;
          sca[t][r] = e;
          psa[r] += e;
        }
      }
    }
    __syncthreads();   // drain g1 stage; Ks[0] reads done

    if (h < 15) stageG(0, 0, 4096, h + 1);  // issue next head g0; covered by QK(g1)

    // ---- QK group 1: strips 4..7 from Ks[1] ----
#pragma unroll
    for (int t = 4; t < 8; ++t) {
      const int sb = t * 128 + w * 16;
      if (sb <= q0b) {
        const ushort* kr = &Ks[1][((t - 4) * 128 + row) * 64];
        bf16x8 k0 = ld_bf16x8(kr + cs0);
        bf16x8 k1 = ld_bf16x8(kr + cs1);
        f32x4 d = {};
        d = __builtin_amdgcn_mfma_f32_16x16x32_bf16(qb0, k0, d, 0, 0, 0);
        d = __builtin_amdgcn_mfma_f32_16x16x32_bf16(qb1, k1, d, 0, 0, 0);
#pragma unroll
        for (int r = 0; r < 4; ++r) {
          float e = __expf(d[r]) * (mqb[r] * ms[t]);
          if (sb == q0b) e = (lr <= lg * 4 + r) ? e : 0.f;
          scb[t][r] = e;
          psb[r] += e;
        }
      }
    }
    // row-sums: 16-lane shfl reduce, then cross-wave via LDS
#pragma unroll
    for (int r = 0; r < 4; ++r) {
      psa[r] += __shfl_xor(psa[r], 1);
      psa[r] += __shfl_xor(psa[r], 2);
      psa[r] += __shfl_xor(psa[r], 4);
      psa[r] += __shfl_xor(psa[r], 8);
      psb[r] += __shfl_xor(psb[r], 1);
      psb[r] += __shfl_xor(psb[r], 2);
      psb[r] += __shfl_xor(psb[r], 4);
      psb[r] += __shfl_xor(psb[r], 8);
    }
    if (lr == 0) {
#pragma unroll
      for (int r = 0; r < 4; ++r) {
        redS[0][w][lg * 4 + r] = psa[r];
        redS[1][w][lg * 4 + r] = psb[r];
      }
    }
    __syncthreads();  // drain next-g0 stage; Ks[1] reads done; redS visible

#pragma unroll
    for (int r = 0; r < 4; ++r) {
      float ta = 0.f, tb = 0.f;
#pragma unroll
      for (int ww = 0; ww < 8; ++ww) {
        ta += redS[0][ww][lg * 4 + r];
        tb += redS[1][ww][lg * 4 + r];
      }
      float ra = __builtin_amdgcn_rcpf(ta);
      float rb = __builtin_amdgcn_rcpf(tb);
#pragma unroll
      for (int t = 0; t < 4; ++t) {
        const int sb = t * 128 + w * 16;
        if (sb <= q0a) acca[t][r] += sca[t][r] * ra;
      }
#pragma unroll
      for (int t = 0; t < 8; ++t) {
        const int sb = t * 128 + w * 16;
        if (sb <= q0b) accb[t][r] += scb[t][r] * rb;
      }
    }
  }  // heads

  // write fp32 attn_avg (d_out) + bf16 copy for strips the AV GEMM reads
#pragma unroll
  for (int t = 0; t < 8; ++t) {
    int s = t * 128 + w * 16 + lr;
#pragma unroll
    for (int r = 0; r < 4; ++r) {
      {
        int q = q0a + lg * 4 + r;
        float v = (t < 4 ? acca[t][r] : 0.f) * 0.0625f;
        long o = ((long)(b * 1024 + q) << 10) + s;
        attn_out[o] = v;
        if (t < NTWa) attnb[o] = f2bf(v);
      }
      {
        int q = q0b + lg * 4 + r;
        float v = accb[t][r] * 0.0625f;
        long o = ((long)(b * 1024 + q) << 10) + s;
        attn_out[o] = v;
        if (t < NTWb) attnb[o] = f2bf(v);
      }
    }
  }
}

// ---------------- launch ----------------
extern "C" void kernel_launch(void* const* d_in, const int* in_sizes, int n_in,
                              void* d_out, int out_size, void* d_ws, size_t ws_size,
                              hipStream_t stream) {
  const float* inputs = (const float*)d_in[0];
  const float* mask   = (const float*)d_in[1];
  const float* W_q    = (const float*)d_in[2];
  const float* W_k    = (const float*)d_in[3];
  const float* W_v    = (const float*)d_in[4];
  const float* W_o    = (const float*)d_in[5];
  float* out = (float*)d_out;

  ushort* Xb    = (ushort*)d_ws;            // [8192][1024]        16 MB
  ushort* XbT   = Xb + 8192L * 1024;        // [B][D][S]           16 MB
  ushort* WqkT  = XbT + 8192L * 1024;       // [2048][1024] B^T     4 MB
  ushort* WoT   = WqkT + 2048L * 1024;      // [1024][1024] Wo^T    2 MB
  ushort* WvoT  = WoT + 1024L * 1024;       // [1024][1024] Wvo^T   2 MB
  ushort* Qb    = WvoT + 1024L * 1024;      // [B,H,S,64]          16 MB
  ushort* Kb    = Qb + 8L * 16 * 1024 * 64; // [B,H,S,64]          16 MB
  ushort* attnb = Kb + 8L * 16 * 1024 * 64; // [B,S,S]             16 MB
  ushort* H2b   = attnb + 8L * 1024 * 1024; // [B,S,D]             16 MB
  // transient aliases (consumed before their regions are written):
  ushort* Wvb = Qb;                         // W_v row-major bf16 (2 MB, read by
                                            // Wvo gemm before QK gemm writes Qb)
  float* WvoP = (float*)attnb;              // 8 fp32 partial planes (32 MB over
                                            // attnb+H2b, read by sum8_pack first)

  // --- packs ---
  pack_x<<<4096, 256, 0, stream>>>(inputs, Xb);
  transpose_pack<<<dim3(16, 16, 8), 256, 0, stream>>>(inputs, XbT, 1024, 1024,
                                                      1048576L, 1048576L, 1.0f);
  transpose_pack<<<dim3(1, 16, 16), 256, 0, stream>>>(W_q, WqkT, 64, 1024,
                                                      65536L, 64L * 1024, 0.125f);
  transpose_pack<<<dim3(1, 16, 16), 256, 0, stream>>>(W_k, WqkT + 1024L * 1024, 64, 1024,
                                                      65536L, 64L * 1024, 1.0f);
  transpose_pack<<<dim3(16, 16, 1), 256, 0, stream>>>(W_o, WoT, 1024, 1024,
                                                      0L, 0L, 1.0f);
  pack_x<<<512, 256, 0, stream>>>(W_v, Wvb);
  // --- Wvo^T = WoT . Wv^T (split-K=8 -> 8 fp32 planes, then sum+pack) ---
  gemm3b<2, false, 0, 8><<<dim3(8, 4, 8), 512, 0, stream>>>(
      WoT, Wvb, 1024, 1024, 128L, 128L, nullptr, nullptr, nullptr, 1048576L, WvoP);
  sum8_pack<<<1024, 256, 0, stream>>>(WvoP, WvoT);
  // --- Q,K projection: [8192,1024] x [1024,2048] (V eliminated) ---
  gemm3b<0, false, 1, 1><<<dim3(16, 32, 1), 512, 0, stream>>>(
      Xb, WqkT, 2048, 1024, 0L, 0L, Qb, Kb, nullptr, 0L, nullptr);
  // --- masked softmax, head-avg ---
  attn16<<<dim3(32, 8), 512, 0, stream>>>(Qb, Kb, mask, out + 8388608L, attnb);
  // --- H2 = attn_avg @ X (causal K-limit), per batch ---
  gemm3b<1, true, 0, 1><<<dim3(8, 4, 8), 512, 0, stream>>>(
      attnb, XbT, 1024, 1024, 1048576L, 1048576L,
      nullptr, nullptr, H2b, 1048576L, nullptr);
  // --- output = H2 @ Wvo ---
  gemm3b<2, false, 1, 1><<<dim3(8, 32, 1), 512, 0, stream>>>(
      H2b, WvoT, 1024, 1024, 0L, 0L, nullptr, nullptr, nullptr, 0L, out);
}